// Round 6
// baseline (67.516 us; speedup 1.0000x reference)
//
#include <hip/hip_runtime.h>
#include <math.h>

// EdgeAwareLoss — round 9: barrier-free wave-autonomous Canny+BCE.
//
// r8 post-mortem: +2 blocks/CU left OccupancyPercent at 37% and regressed
// (halo overhead). The block-wide 6-barrier pipeline convoys every wave to
// the slowest stage; no grid shape fixes that. r9 removes ALL barriers and
// ALL LDS from the heavy kernel: each wave owns a 2-row x 1024-col strip;
// each lane solo-computes one 32-px ez word via r5's validated 40-bit
// single-u64 window math (9 stitched windows -> 7 Sobel rows -> 5 NMS rows
// -> ez), then the wave streams pred coalesced, fetching ez/target bits
// from producer lanes via __shfl. 8192 independent waves, straight-line
// code, 27 upfront loads per lane = max MLP.
//
// Exactness (bit-sliced pipeline validated absmax 0.0 r5-r8):
//  - img=(t>0.5)*255 => m multiple of 255 => weak==strong => strong==cand.
//  - gx,gy in [-4,4] (255-units), m=|gx|+|gy|<=6: 3 bit-planes.
//  - horiz: ay==0&&ax>=1 || ay==1&&ax>=3 ; vert: ax==0&&ay>=1 || ax==1&&ay>=3
//  - NMS row trick: P=(m>left); kH = P & ~(P>>1).
//  - 40-bit window, bit j = col 32*w32-4+j; m valid j=1..38, cand j=2..37,
//    output px j=4..35 (colmask + interior masks identical to r5).
//  - bce = -max(log(t?p:1-p),-100); 1-p exact for p>=0.5 (Sterbenz).

typedef unsigned long long u64;
typedef unsigned int u32;

#define H_IMG 1024
#define W_IMG 1024
#define WPR 32                 // packed u32 words per image row

// ---- kernel 1: binarize target to 1 bit/px (verbatim r3, 6.7 TB/s) ----
__global__ __launch_bounds__(256)
void binarize_kernel(const float* __restrict__ target, u32* __restrict__ packed,
                     int nwords)
{
    int t = blockIdx.x * 256 + threadIdx.x;
    if (t >= nwords) return;
    const float4* src = (const float4*)target + (size_t)t * 8;
    u32 v = 0;
#pragma unroll
    for (int k = 0; k < 8; ++k) {
        float4 f = src[k];
        v |= (f.x > 0.5f ? 1u : 0u) << (4 * k);
        v |= (f.y > 0.5f ? 2u : 0u) << (4 * k);
        v |= (f.z > 0.5f ? 4u : 0u) << (4 * k);
        v |= (f.w > 0.5f ? 8u : 0u) << (4 * k);
    }
    packed[t] = v;
}

__device__ __forceinline__ u64 gt3(u64 a2, u64 a1, u64 a0,
                                   u64 b2, u64 b1, u64 b0)
{
    u64 e2 = ~(a2 ^ b2), g2 = a2 & ~b2;
    u64 e1 = ~(a1 ^ b1), g1 = a1 & ~b1;
    u64 g0 = a0 & ~b0;
    return g2 | (e2 & (g1 | (e1 & g0)));
}

// ---- kernel 2: wave-autonomous Canny + BCE (no LDS, no barriers) ----
// wave gw owns image rows [R0, R0+1]; lane = (s<<5)|w32 computes the ez word
// for image row R0+s, cols 32*w32 .. 32*w32+31.
__global__ __launch_bounds__(256)
void canny_bce_kernel(const float* __restrict__ pred,
                      const u32* __restrict__ tbits,
                      float* __restrict__ partials)
{
    const int tid = threadIdx.x;
    const int lane = tid & 63;
    const int gw = (blockIdx.x << 2) | (tid >> 6);
    const int s = lane >> 5, w32 = lane & 31;
    const int img = gw >> 9;
    const int R0 = (gw & 511) << 1;
    const u32* tb = tbits + (size_t)img * (H_IMG * WPR);

    // 9 stitched 40-bit windows: rows R0+s-4 .. R0+s+4 (row clamp = edge pad)
    u64 blw[9];
#pragma unroll
    for (int i = 0; i < 9; ++i) {
        int r = R0 + s - 4 + i; r = r < 0 ? 0 : (r > H_IMG - 1 ? H_IMG - 1 : r);
        const u32* prow = tb + r * WPR;
        u32 wB = prow[w32];
        u32 wA = w32 ? prow[w32 - 1] : ((wB & 1u) ? ~0u : 0u);
        u32 wC = (w32 < WPR - 1) ? prow[w32 + 1] : ((wB >> 31) ? ~0u : 0u);
        blw[i] = (u64)(wA >> 28) | ((u64)wB << 4) | ((u64)(wC & 0xFu) << 36);
    }

    // Sobel for 7 m-rows: m index i = image row R0+s-3+i (from blw[i..i+2])
    u64 m0a[7], m1a[7], m2a[7], hza[7], vta[7], sda[7];
#pragma unroll
    for (int i = 0; i < 7; ++i) {
        u64 A = blw[i], Bq = blw[i + 1], C = blw[i + 2];
        u64 AL = A << 1, AR = A >> 1;
        u64 BL = Bq << 1, BR = Bq >> 1;
        u64 CL = C << 1, CR = C >> 1;

        u64 sx = AR ^ CR, cxk = AR & CR;
        u64 Px1 = BR ^ cxk, Px2 = BR & cxk;
        u64 sn = AL ^ CL, cnk = AL & CL;
        u64 Nx1 = BL ^ cnk, Nx2 = BL & cnk;
        u64 d0 = sx ^ sn;
        u64 ca = sx | ~sn;
        u64 nb1 = ~Nx1, t1 = Px1 ^ nb1, d1 = t1 ^ ca;
        u64 cb = (Px1 & nb1) | (ca & t1);
        u64 nb2 = ~Nx2, t2 = Px2 ^ nb2, d2 = t2 ^ cb;
        u64 cc = (Px2 & nb2) | (cb & t2);
        u64 sgx = ~cc;                         // gx < 0
        u64 ax0 = d0;
        u64 ax1 = d1 ^ (sgx & d0);
        u64 ax2 = d2 ^ (sgx & (d0 | d1));

        u64 sy = CL ^ CR, cyk = CL & CR;
        u64 Py1 = C ^ cyk, Py2 = C & cyk;
        u64 sm = AL ^ AR, cmk = AL & AR;
        u64 Ny1 = A ^ cmk, Ny2 = A & cmk;
        u64 e0 = sy ^ sm;
        u64 ka = sy | ~sm;
        u64 mb1 = ~Ny1, u1 = Py1 ^ mb1, f1 = u1 ^ ka;
        u64 kb = (Py1 & mb1) | (ka & u1);
        u64 mb2 = ~Ny2, u2 = Py2 ^ mb2, f2 = u2 ^ kb;
        u64 kc = (Py2 & mb2) | (kb & u2);
        u64 sgy = ~kc;                         // gy < 0
        u64 ay0 = e0;
        u64 ay1 = f1 ^ (sgy & e0);
        u64 ay2 = f2 ^ (sgy & (e0 | f1));

        u64 s0 = ax0 ^ ay0, q0 = ax0 & ay0;
        u64 tt = ax1 ^ ay1, s1 = tt ^ q0;
        u64 q1 = (ax1 & ay1) | (q0 & tt);
        u64 s2 = ax2 ^ ay2 ^ q1;
        m0a[i] = s0; m1a[i] = s1; m2a[i] = s2;

        u64 ax12 = ax1 | ax2, axnz = ax0 | ax12;
        u64 axe1 = ax0 & ~ax12, axg3 = ax2 | (ax1 & ax0);
        u64 ay12 = ay1 | ay2, aynz = ay0 | ay12;
        u64 aye1 = ay0 & ~ay12, ayg3 = ay2 | (ay1 & ay0);
        hza[i] = (axnz & ~aynz) | (aye1 & axg3);
        vta[i] = (aynz & ~axnz) | (axe1 & ayg3);
        u64 gxp = axnz & ~sgx, gyp = aynz & ~sgy;
        sda[i] = (gxp & sgy) | (sgx & gyp);
    }

    // NMS + threshold + masks; fused horiz 5-OR and vertical 5-OR
    const u64 colmask = (~0ULL << ((w32 == 0) ? 5 : 2)) &
                        (~0ULL >> (63 - ((w32 == WPR - 1) ? 34 : 37)));
    u64 ez = 0;
#pragma unroll
    for (int cr = 0; cr < 5; ++cr) {          // cand row = R0+s-2+cr
        u64 M0c = m0a[cr + 1], M1c = m1a[cr + 1], M2c = m2a[cr + 1];
        u64 U0c = m0a[cr],     U1c = m1a[cr],     U2c = m2a[cr];
        u64 D0c = m0a[cr + 2], D1c = m1a[cr + 2], D2c = m2a[cr + 2];

        u64 P = gt3(M2c, M1c, M0c, M2c << 1, M1c << 1, M0c << 1);  // m > left
        u64 kH = P & ~(P >> 1);                                    // & m>=right
        u64 kV = gt3(M2c, M1c, M0c, U2c, U1c, U0c) &
                ~gt3(D2c, D1c, D0c, M2c, M1c, M0c);
        u64 kA = gt3(M2c, M1c, M0c, U2c >> 1, U1c >> 1, U0c >> 1) &
                ~gt3(D2c << 1, D1c << 1, D0c << 1, M2c, M1c, M0c);
        u64 kB = gt3(M2c, M1c, M0c, U2c << 1, U1c << 1, U0c << 1) &
                ~gt3(D2c >> 1, D1c >> 1, D0c >> 1, M2c, M1c, M0c);

        u64 H = hza[cr + 1], V = vta[cr + 1], S = sda[cr + 1];
        u64 nHV = ~(H | V);
        u64 keep = (H & kH) | (V & kV) | (nHV & ((S & kA) | (~S & kB)));
        u64 cand = keep & (M0c | M1c | M2c) & colmask;
        int rr = R0 + s - 2 + cr;
        if (rr < 1 || rr > H_IMG - 2) cand = 0;
        ez |= cand | (cand << 1) | (cand << 2) | (cand >> 1) | (cand >> 2);
    }
    u32 ez32 = (u32)(ez >> 4);                // px cols 32*w32 .. +31
    u32 tbw  = (u32)(blw[4] >> 4);            // target bits, same cols, row R0+s

    // BCE over the wave's 2-row strip (coalesced float4; bits via shuffle)
    const float4* pp4 = (const float4*)(pred + ((size_t)img << 20) + ((size_t)R0 << 10));
    float acc = 0.0f;
#pragma unroll
    for (int k = 0; k < 8; ++k) {
        float4 pv = pp4[k * 64 + lane];
        int src = ((k >> 2) << 5) | ((k * 8 + (lane >> 3)) & 31);
        u32 ew = ((u32)__shfl((int)ez32, src, 64)) >> ((lane & 7) * 4);
        u32 tw = ((u32)__shfl((int)tbw,  src, 64)) >> ((lane & 7) * 4);
        float ps[4] = {pv.x, pv.y, pv.z, pv.w};
#pragma unroll
        for (int c2 = 0; c2 < 4; ++c2) {
            float p = ps[c2];
            float xx = ((tw >> c2) & 1u) ? p : 1.0f - p;
            float lg = fmaxf(__logf(xx), -100.0f);
            acc = fmaf(((ew >> c2) & 1u) ? 5.0f : 1.0f, -lg, acc);
        }
    }

    for (int off = 32; off > 0; off >>= 1)
        acc += __shfl_down(acc, off);
    if (lane == 0) partials[gw] = acc;
}

__global__ __launch_bounds__(256)
void finalize_kernel(const float* __restrict__ partials, float* __restrict__ out,
                     int nblocks, double invN)
{
    __shared__ double ws[4];
    double s = 0.0;
    for (int i = threadIdx.x; i < nblocks; i += 256) s += (double)partials[i];
    for (int off = 32; off > 0; off >>= 1) s += __shfl_down(s, off);
    int wid = threadIdx.x >> 6, lane = threadIdx.x & 63;
    if (lane == 0) ws[wid] = s;
    __syncthreads();
    if (threadIdx.x == 0) out[0] = (float)((ws[0] + ws[1] + ws[2] + ws[3]) * invN);
}

extern "C" void kernel_launch(void* const* d_in, const int* in_sizes, int n_in,
                              void* d_out, int out_size, void* d_ws, size_t ws_size,
                              hipStream_t stream)
{
    (void)n_in; (void)out_size; (void)ws_size;
    const float* pred   = (const float*)d_in[0];
    const float* target = (const float*)d_in[1];
    const int N = in_sizes[0];
    const int B = N / (H_IMG * W_IMG);

    // ws layout: [0,64KB) per-wave partials; [64KB, +2MB) target bits
    float* partials = (float*)d_ws;
    u32* tbits = (u32*)((char*)d_ws + 65536);
    const int nwords = B * H_IMG * WPR;          // 524288 (2 MB) for B=16

    binarize_kernel<<<(nwords + 255) / 256, 256, 0, stream>>>(target, tbits, nwords);

    const int nwaves = B * (H_IMG / 2);          // 8192 for B=16
    canny_bce_kernel<<<nwaves / 4, 256, 0, stream>>>(pred, tbits, partials);

    finalize_kernel<<<1, 256, 0, stream>>>(partials, (float*)d_out, nwaves,
                                           1.0 / (double)N);
}